// Round 2
// baseline (2834.515 us; speedup 1.0000x reference)
//
#include <hip/hip_runtime.h>

typedef unsigned int u32;
typedef unsigned short u16;

#define N_NODES 50000
#define DIM     160
#define M0      64
#define M1      32
#define NP0     2016   // len(triu_indices(64, k=1))
#define NP1     496    // len(triu_indices(32, k=1))
#define NB      64     // nodes per block
#define XSTR    162    // padded LDS stride (162 % 32 == 2 -> conflict-free)

__device__ __forceinline__ void fma4(float* acc, float s, float4 w) {
    acc[0] += s * w.x; acc[1] += s * w.y; acc[2] += s * w.z; acc[3] += s * w.w;
}

__global__ __launch_bounds__(256)
void node_block_kernel(const float* __restrict__ feats, const float* __restrict__ msgs,
                       const float* __restrict__ W1, const float* __restrict__ W2,
                       const float* __restrict__ W3, const float* __restrict__ W4,
                       const float* __restrict__ W5, float* __restrict__ out) {
    __shared__ float xs[NB * XSTR];
    __shared__ u16 tab0[NP0];
    __shared__ u16 tab1[NP1];

    const int tid = threadIdx.x;

    // --- triu(k=1) pair tables, row-major (u,v) order == np.triu_indices ---
    for (int u = tid; u < M0 - 1; u += 256) {
        int base = u * (2 * M0 - u - 1) / 2;
        for (int v = u + 1; v < M0; ++v) tab0[base + v - u - 1] = (u16)((u << 8) | v);
    }
    for (int u = tid; u < M1 - 1; u += 256) {
        int base = u * (2 * M1 - u - 1) / 2;
        for (int v = u + 1; v < M1; ++v) tab1[base + v - u - 1] = (u16)((u << 8) | v);
    }

    // --- stage x = feats + msgs (f32) for NB nodes ---
    const int node0 = blockIdx.x * NB;
    const int gbase = node0 * DIM;
    for (int chunk = tid; chunk < NB * DIM / 4; chunk += 256) {
        int idx = chunk * 4;            // 160 % 4 == 0: never straddles nodes
        int nl = idx / DIM;
        int d  = idx - nl * DIM;
        int g  = gbase + idx;
        float4 v;
        if (g + 4 <= N_NODES * DIM) {
            float4 fa = *(const float4*)(feats + g);
            float4 fb = *(const float4*)(msgs + g);
            v.x = fa.x + fb.x; v.y = fa.y + fb.y;
            v.z = fa.z + fb.z; v.w = fa.w + fb.w;
        } else {
            v.x = v.y = v.z = v.w = 0.f;
        }
        float* dst = &xs[nl * XSTR + d];
        dst[0] = v.x; dst[1] = v.y; dst[2] = v.z; dst[3] = v.w;
    }
    __syncthreads();

    const int nl = tid >> 2;       // 64 nodes/block
    const int c  = tid & 3;        // 4 column groups
    const int node = node0 + nl;
    const float* xr = &xs[nl * XSTR];

    const float INV_SQRT3 = 0.57735026918962576f;

    // ================= out0: cols [c*16, c*16+16) =================
    float a0[16];
    #pragma unroll
    for (int j = 0; j < 16; ++j) a0[j] = 0.f;

    // pair0 @ W1
    for (int p = 0; p < NP0; ++p) {
        int pk = tab0[p];
        float pv = xr[pk >> 8] * xr[pk & 255];
        const float4* wp = (const float4*)(W1 + p * M0 + c * 16);
        fma4(a0,      pv, wp[0]);
        fma4(a0 + 4,  pv, wp[1]);
        fma4(a0 + 8,  pv, wp[2]);
        fma4(a0 + 12, pv, wp[3]);
    }
    // sq0 @ W2
    for (int p = 0; p < M0; ++p) {
        float sv = xr[p] * xr[p];
        const float4* wp = (const float4*)(W2 + p * M0 + c * 16);
        fma4(a0,      sv, wp[0]);
        fma4(a0 + 4,  sv, wp[1]);
        fma4(a0 + 8,  sv, wp[2]);
        fma4(a0 + 12, sv, wp[3]);
    }
    // pair1 @ W4   (pair1[uv] = <x1[u],x1[v]> / sqrt(3))
    for (int p = 0; p < NP1; ++p) {
        int pk = tab1[p];
        const float* a = xr + M0 + (pk >> 8) * 3;
        const float* b = xr + M0 + (pk & 255) * 3;
        float dv = (a[0] * b[0] + a[1] * b[1] + a[2] * b[2]) * INV_SQRT3;
        const float4* wp = (const float4*)(W4 + p * M0 + c * 16);
        fma4(a0,      dv, wp[0]);
        fma4(a0 + 4,  dv, wp[1]);
        fma4(a0 + 8,  dv, wp[2]);
        fma4(a0 + 12, dv, wp[3]);
    }
    // diag1 @ W5
    for (int u = 0; u < M1; ++u) {
        const float* a = xr + M0 + u * 3;
        float dv = (a[0] * a[0] + a[1] * a[1] + a[2] * a[2]) * INV_SQRT3;
        const float4* wp = (const float4*)(W5 + u * M0 + c * 16);
        fma4(a0,      dv, wp[0]);
        fma4(a0 + 4,  dv, wp[1]);
        fma4(a0 + 8,  dv, wp[2]);
        fma4(a0 + 12, dv, wp[3]);
    }

    if (node < N_NODES) {
        const float C0v = 0.019581512f;   // sqrt(1/2608)
        float4* op = (float4*)(out + node * DIM + c * 16);
        #pragma unroll
        for (int q = 0; q < 4; ++q) {
            float4 o;
            o.x = C0v * a0[q * 4 + 0];
            o.y = C0v * a0[q * 4 + 1];
            o.z = C0v * a0[q * 4 + 2];
            o.w = C0v * a0[q * 4 + 3];
            op[q] = o;
        }
    }

    // ================= out1: w in [c*8, c*8+8), all i =================
    // out1[n][w][i] = sum_u x1[u][i] * ( sum_v x0[v] * W3[u][v][w] )
    float a1[24];
    #pragma unroll
    for (int k = 0; k < 24; ++k) a1[k] = 0.f;

    for (int u = 0; u < M1; ++u) {
        float t[8];
        #pragma unroll
        for (int w = 0; w < 8; ++w) t[w] = 0.f;
        const float* wrow = W3 + (u * M0) * M1 + c * 8;   // W3[u][v][w]: (u*64+v)*32+w
        for (int v = 0; v < M0; ++v) {
            float xv = xr[v];
            const float4* wq = (const float4*)(wrow + v * M1);
            float4 q0 = wq[0], q1 = wq[1];
            t[0] += xv * q0.x; t[1] += xv * q0.y; t[2] += xv * q0.z; t[3] += xv * q0.w;
            t[4] += xv * q1.x; t[5] += xv * q1.y; t[6] += xv * q1.z; t[7] += xv * q1.w;
        }
        const float* xu = xr + M0 + u * 3;
        #pragma unroll
        for (int w = 0; w < 8; ++w) {
            a1[w * 3 + 0] += xu[0] * t[w];
            a1[w * 3 + 1] += xu[1] * t[w];
            a1[w * 3 + 2] += xu[2] * t[w];
        }
    }

    if (node < N_NODES) {
        const float S1 = 0.022097087f;  // C1 / sqrt(3) == sqrt(1/2048)
        float* op = out + node * DIM + M0 + c * 24;   // cols 64+c*24 .. +24 (w*3+i)
        #pragma unroll
        for (int q = 0; q < 6; ++q) {
            float4 o;
            o.x = S1 * a1[q * 4 + 0];
            o.y = S1 * a1[q * 4 + 1];
            o.z = S1 * a1[q * 4 + 2];
            o.w = S1 * a1[q * 4 + 3];
            *(float4*)(op + q * 4) = o;
        }
    }
}

extern "C" void kernel_launch(void* const* d_in, const int* in_sizes, int n_in,
                              void* d_out, int out_size, void* d_ws, size_t ws_size,
                              hipStream_t stream) {
    const float* feats = (const float*)d_in[0];
    const float* msgs  = (const float*)d_in[1];
    const float* W1    = (const float*)d_in[2];
    const float* W2    = (const float*)d_in[3];
    const float* W3    = (const float*)d_in[4];
    const float* W4    = (const float*)d_in[5];
    const float* W5    = (const float*)d_in[6];
    float* out = (float*)d_out;

    dim3 grid((N_NODES + NB - 1) / NB);   // 782
    dim3 block(256);
    hipLaunchKernelGGL(node_block_kernel, grid, block, 0, stream,
                       feats, msgs, W1, W2, W3, W4, W5, out);
}

// Round 3
// 380.829 us; speedup vs baseline: 7.4430x; 7.4430x over previous
//
#include <hip/hip_runtime.h>
#include <hip/hip_bf16.h>

typedef unsigned short u16;
typedef unsigned int u32;

#define N_NODES 50000
#define DIM     160
#define NB      64        // nodes per block
#define XSTR    162       // xs f32 row stride
#define K1      2608
#define K1PAD   2688      // 42 K-tiles of 64
#define NT1     42
#define STR1    72        // A1/B1 LDS row stride (u16), 144B: 16B-aligned rows
#define K2      2048      // 16 K-tiles of 128
#define NT2     16
#define STR2    136       // A2/B2 LDS row stride (u16), 272B: 16B-aligned rows

#define WCAT_ELEMS (K1PAD * 64)   // 172032 u16
#define W3F_OFF    WCAT_ELEMS
#define W3F_ELEMS  (K2 * 32)      // 65536 u16

typedef __attribute__((ext_vector_type(8))) short short8;
typedef __attribute__((ext_vector_type(4))) float f32x4;
union U4S8 { uint4 u; short8 s; };

__device__ __forceinline__ u16 f2bf(float f) {   // RNE f32->bf16
    u32 u = __float_as_uint(f);
    return (u16)((u + 0x7fffu + ((u >> 16) & 1u)) >> 16);
}

// ---------------- pack kernel: weights -> bf16, K-tile-contiguous [n][k] ----------------
__global__ __launch_bounds__(256)
void pack_kernel(const float* __restrict__ W1, const float* __restrict__ W2,
                 const float* __restrict__ W3, const float* __restrict__ W4,
                 const float* __restrict__ W5, u16* __restrict__ ws) {
    int t = blockIdx.x * 256 + threadIdx.x;
    if (t < K1PAD * 64) {
        int k = t >> 6, n = t & 63;
        float val = 0.f;
        if      (k < 2016) val = W1[k * 64 + n];
        else if (k < 2080) val = W2[(k - 2016) * 64 + n];
        else if (k < 2576) val = W4[(k - 2080) * 64 + n];
        else if (k < 2608) val = W5[(k - 2576) * 64 + n];
        int kt = k >> 6, kk = k & 63;
        ws[kt * 4096 + n * 64 + kk] = f2bf(val);
    } else {
        int t2 = t - K1PAD * 64;
        if (t2 < K2 * 32) {
            int k = t2 >> 5, w = t2 & 31;       // k = u*64+v
            float val = W3[k * 32 + w];
            int kt = k >> 7, kk = k & 127;
            ws[W3F_OFF + kt * 4096 + w * 128 + kk] = f2bf(val);
        }
    }
}

// ---------------- main fused kernel ----------------
__global__ __launch_bounds__(256, 2)
void node_block_kernel(const float* __restrict__ feats, const float* __restrict__ msgs,
                       const u16* __restrict__ ws, float* __restrict__ out) {
    __shared__ float xs[NB * XSTR];       // 41472 B
    __shared__ u16 kmeta[K1PAD];          //  5376 B
    __shared__ u16 tiles[17408];          // 34816 B (union: phase1 A1+B1 / phase2 A2+B2)
    u16* A1 = tiles;            u16* B1 = tiles + 64 * STR1;   // 4608
    u16* A2 = tiles;            u16* B2 = tiles + 96 * STR2;   // 13056

    const int tid = threadIdx.x;

    // --- kmeta: per-K-row (type | u<<6 | v) ---
    for (int u = tid; u < 63; u += 256) {
        int base = u * (127 - u) / 2;                      // u*(2*64-u-1)/2
        for (int v = u + 1; v < 64; ++v) kmeta[base + v - u - 1] = (u16)((u << 6) | v);
    }
    for (int j = tid; j < 64; j += 256) kmeta[2016 + j] = (u16)((j << 6) | j);
    for (int u = tid; u < 31; u += 256) {
        int base = 2080 + u * (63 - u) / 2;                // u*(2*32-u-1)/2
        for (int v = u + 1; v < 32; ++v) kmeta[base + v - u - 1] = (u16)((1 << 12) | (u << 6) | v);
    }
    for (int u = tid; u < 32; u += 256) kmeta[2576 + u] = (u16)((1 << 12) | (u << 6) | u);
    for (int k = 2608 + tid; k < K1PAD; k += 256) kmeta[k] = (u16)(2 << 12);

    // --- stage x = feats + msgs (f32) ---
    const int node0 = blockIdx.x * NB;
    const int gbase = node0 * DIM;
    for (int chunk = tid; chunk < NB * DIM / 4; chunk += 256) {
        int idx = chunk * 4;
        int nl = idx / DIM;
        int d  = idx - nl * DIM;
        int g  = gbase + idx;
        float4 v;
        if (g + 4 <= N_NODES * DIM) {
            float4 fa = *(const float4*)(feats + g);
            float4 fb = *(const float4*)(msgs + g);
            v.x = fa.x + fb.x; v.y = fa.y + fb.y; v.z = fa.z + fb.z; v.w = fa.w + fb.w;
        } else { v.x = v.y = v.z = v.w = 0.f; }
        float* dst = &xs[nl * XSTR + d];
        dst[0] = v.x; dst[1] = v.y; dst[2] = v.z; dst[3] = v.w;
    }
    __syncthreads();

    const int wave = tid >> 6, lane = tid & 63, quad = lane >> 4, l15 = lane & 15;

    // =============== Phase 1: out0 = C0 * (P @ Wcat), M=64 N=64 K=2688 ===============
    f32x4 acc[4];
    #pragma unroll
    for (int mt = 0; mt < 4; ++mt) acc[mt] = (f32x4){0.f, 0.f, 0.f, 0.f};

    const int bm = tid >> 2;              // build: row m
    const int bk = (tid & 3) * 16;        // build: kk base
    const float* xrb = &xs[bm * XSTR];
    const float INV_SQRT3 = 0.57735026918962576f;

    for (int kt = 0; kt < NT1; ++kt) {
        const int k0 = kt * 64;
        // build A1 tile: 16 entries per thread
        #pragma unroll
        for (int j = 0; j < 16; j += 2) {
            float vv[2];
            #pragma unroll
            for (int s = 0; s < 2; ++s) {
                u16 mt = kmeta[k0 + bk + j + s];
                int ty = mt >> 12, u = (mt >> 6) & 63, v = mt & 63;
                float val = 0.f;
                if (ty == 0) val = xrb[u] * xrb[v];
                else if (ty == 1) {
                    const float* a = xrb + 64 + u * 3;
                    const float* b = xrb + 64 + v * 3;
                    val = (a[0] * b[0] + a[1] * b[1] + a[2] * b[2]) * INV_SQRT3;
                }
                vv[s] = val;
            }
            *(__hip_bfloat162*)&A1[bm * STR1 + bk + j] =
                __float22bfloat162_rn(make_float2(vv[0], vv[1]));
        }
        // stage B1 tile: [n][kk] 64x64 (8KB), coalesced
        {
            int n = tid >> 2, sub = tid & 3;
            const uint4* src = (const uint4*)(ws + kt * 4096 + n * 64 + sub * 16);
            uint4 a = src[0], b = src[1];
            *(uint4*)&B1[n * STR1 + sub * 16] = a;
            *(uint4*)&B1[n * STR1 + sub * 16 + 8] = b;
        }
        __syncthreads();
        // MFMA: wave = n-tile; 4 m-tiles x 2 k-steps
        #pragma unroll
        for (int ks = 0; ks < 2; ++ks) {
            U4S8 bf; bf.u = *(const uint4*)&B1[(wave * 16 + l15) * STR1 + ks * 32 + quad * 8];
            #pragma unroll
            for (int mt = 0; mt < 4; ++mt) {
                U4S8 af; af.u = *(const uint4*)&A1[(mt * 16 + l15) * STR1 + ks * 32 + quad * 8];
                acc[mt] = __builtin_amdgcn_mfma_f32_16x16x32_bf16(af.s, bf.s, acc[mt], 0, 0, 0);
            }
        }
        __syncthreads();
    }
    // epilogue 1
    {
        const float C0v = 0.019581512f;   // sqrt(1/2608)
        #pragma unroll
        for (int mt = 0; mt < 4; ++mt) {
            #pragma unroll
            for (int r = 0; r < 4; ++r) {
                int row = mt * 16 + quad * 4 + r;
                int node = node0 + row;
                if (node < N_NODES) out[node * DIM + wave * 16 + l15] = C0v * acc[mt][r];
            }
        }
    }

    // =============== Phase 2: out1' = S1 * (Q @ W3f), M=192 N=32 K=2048 ===============
    // rows r = i*64 + m; Q[r][u*64+v] = x1[m][u][i] * x0[m][v]; done in 2 halves of 96 rows
    const int nt2 = wave & 1, mtb = (wave >> 1) * 3;
    const int rl = tid >> 1, uh = tid & 1;          // build mapping (tid < 192)

    for (int h = 0; h < 2; ++h) {
        f32x4 acc2[3];
        #pragma unroll
        for (int mt = 0; mt < 3; ++mt) acc2[mt] = (f32x4){0.f, 0.f, 0.f, 0.f};

        int r = h * 96 + rl;
        int m2 = r & 63, i2 = r >> 6;
        const float* xm = &xs[m2 * XSTR];

        for (int kt = 0; kt < NT2; ++kt) {
            if (tid < 192) {       // build A2 rows [h*96, h*96+96)
                int u = kt * 2 + uh;
                float x1v = xm[64 + u * 3 + i2];
                u16* dst = &A2[rl * STR2 + uh * 64];
                #pragma unroll
                for (int v = 0; v < 64; v += 2) {
                    float2 x0 = *(const float2*)&xm[v];
                    *(__hip_bfloat162*)&dst[v] =
                        __float22bfloat162_rn(make_float2(x0.x * x1v, x0.y * x1v));
                }
            }
            // stage B2 tile: [w][kk] 32x128 (8KB)
            {
                int w = tid >> 3, sub = tid & 7;
                const uint4* src = (const uint4*)(ws + W3F_OFF + kt * 4096 + w * 128 + sub * 16);
                uint4 a = src[0], b = src[1];
                *(uint4*)&B2[w * STR2 + sub * 16] = a;
                *(uint4*)&B2[w * STR2 + sub * 16 + 8] = b;
            }
            __syncthreads();
            #pragma unroll
            for (int ks = 0; ks < 4; ++ks) {
                U4S8 bf; bf.u = *(const uint4*)&B2[(nt2 * 16 + l15) * STR2 + ks * 32 + quad * 8];
                #pragma unroll
                for (int mt = 0; mt < 3; ++mt) {
                    U4S8 af; af.u = *(const uint4*)&A2[((mtb + mt) * 16 + l15) * STR2 + ks * 32 + quad * 8];
                    acc2[mt] = __builtin_amdgcn_mfma_f32_16x16x32_bf16(af.s, bf.s, acc2[mt], 0, 0, 0);
                }
            }
            __syncthreads();
        }
        // epilogue 2 (half h)
        {
            const float S1 = 0.022097087f;  // C1/sqrt(3) = sqrt(1/2048)
            #pragma unroll
            for (int mt = 0; mt < 3; ++mt) {
                #pragma unroll
                for (int rr = 0; rr < 4; ++rr) {
                    int r2 = h * 96 + (mtb + mt) * 16 + quad * 4 + rr;
                    int m = r2 & 63, i = r2 >> 6;
                    int w = nt2 * 16 + l15;
                    int node = node0 + m;
                    if (node < N_NODES) out[node * DIM + 64 + w * 3 + i] = S1 * acc2[mt][rr];
                }
            }
        }
    }
}

extern "C" void kernel_launch(void* const* d_in, const int* in_sizes, int n_in,
                              void* d_out, int out_size, void* d_ws, size_t ws_size,
                              hipStream_t stream) {
    const float* feats = (const float*)d_in[0];
    const float* msgs  = (const float*)d_in[1];
    const float* W1    = (const float*)d_in[2];
    const float* W2    = (const float*)d_in[3];
    const float* W3    = (const float*)d_in[4];
    const float* W4    = (const float*)d_in[5];
    const float* W5    = (const float*)d_in[6];
    float* out = (float*)d_out;
    u16* ws = (u16*)d_ws;   // needs (172032 + 65536) * 2 = 475136 B

    // pack weights -> bf16 tiles in ws (re-done every call; ws is re-poisoned)
    int pack_threads = K1PAD * 64 + K2 * 32;          // 237568
    hipLaunchKernelGGL(pack_kernel, dim3(pack_threads / 256), dim3(256), 0, stream,
                       W1, W2, W3, W4, W5, ws);

    hipLaunchKernelGGL(node_block_kernel, dim3((N_NODES + NB - 1) / NB), dim3(256), 0, stream,
                       feats, msgs, ws, out);
}